// Round 5
// baseline (184.082 us; speedup 1.0000x reference)
//
#include <hip/hip_runtime.h>
#include <hip/hip_bf16.h>
#include <stdint.h>

// FlatCritic: B=128, L=512, D_DESC=768, D_STD=128, D_ACT=128, D_CTX=1152, H=512
// out = [q (B*L f32), emb (B*L*128 f32)]
//
// v5: emb = barrier-free per-wave MFMA with A-frags loaded DIRECT from global
// (A[m=lane&15][k=(lane>>4)*8+j] == per-lane contiguous 32B of an action row),
// B = pre-packed W fragments; wave-private LDS bounce only for the embB export.
// mlp = v4 + explicit 1-deep fragment prefetch (static ks&1 indexing).

typedef __attribute__((ext_vector_type(8))) short short8_t;
typedef __attribute__((ext_vector_type(4))) short short4_t;
typedef __attribute__((ext_vector_type(4))) float f32x4;
typedef __attribute__((ext_vector_type(4))) unsigned int u32x4;

__device__ inline unsigned short f2bf(float f) {
  union { float f; unsigned u; } v; v.f = f;
  unsigned r = v.u + 0x7FFFu + ((v.u >> 16) & 1u);
  return (unsigned short)(r >> 16);
}

__device__ inline unsigned short cvt1(float f) {  // compiler-friendly RNE cvt (fuses to cvt_pk)
  __hip_bfloat16 h = __float2bfloat16(f);
  unsigned short u; __builtin_memcpy(&u, &h, 2);
  return u;
}

__device__ inline short8_t cvt8m(f32x4 lo, f32x4 hi, unsigned m) {
  short8_t r;
  r[0] = (short)cvt1(lo[0]); r[1] = (short)cvt1(lo[1]);
  r[2] = (short)cvt1(lo[2]); r[3] = (short)cvt1(lo[3]);
  r[4] = (short)cvt1(hi[0]); r[5] = (short)cvt1(hi[1]);
  r[6] = (short)cvt1(hi[2]); r[7] = (short)cvt1(hi[3]);
  u32x4 u; __builtin_memcpy(&u, &r, 16);
  u[0] &= m; u[1] &= m; u[2] &= m; u[3] &= m;
  short8_t o; __builtin_memcpy(&o, &u, 16);
  return o;
}

// A-frag pack (mb-major): dst[((mb*NKS+ks)*64+l)*8+j] = bf16(src[(k0+ks*32+(l>>4)*8+j)*ldc + mb*16+(l&15)])
__device__ inline void pack_frags(const float* __restrict__ src, int ldc, int k0, int NKS,
                                  unsigned short* __restrict__ dst, int total, int tid, int n) {
  for (int fi = tid; fi < total; fi += n) {
    int j = fi & 7, lane = (fi >> 3) & 63, rest = fi >> 9;
    int ks = rest % NKS, mb = rest / NKS;
    int c = mb * 16 + (lane & 15);
    int k = k0 + ks * 32 + ((lane >> 4) << 3) + j;
    dst[fi] = f2bf(src[(size_t)k * ldc + c]);
  }
}

// B-frag pack (k-major): dst[((kq*8+nb)*64+l)*8+j] = bf16(src[(kq*32+(l>>4)*8+j)*ldc + nb*16+(l&15)])
__device__ inline void pack_fragsB(const float* __restrict__ src, int ldc,
                                   unsigned short* __restrict__ dst, int total, int tid, int n) {
  for (int fi = tid; fi < total; fi += n) {
    int j = fi & 7, lane = (fi >> 3) & 63, rest = fi >> 9;
    int nb = rest & 7, kq = rest >> 3;
    int c = nb * 16 + (lane & 15);
    int k = kq * 32 + ((lane >> 4) << 3) + j;
    dst[fi] = f2bf(src[(size_t)k * ldc + c]);
  }
}

__global__ __launch_bounds__(256) void prep_pack(
    const float* __restrict__ Wd, const float* __restrict__ Ws,
    const float* __restrict__ W1, const float* __restrict__ W2,
    unsigned short* __restrict__ wdB, unsigned short* __restrict__ wsB,
    unsigned short* __restrict__ w1f, unsigned short* __restrict__ w2f) {
  int tid = blockIdx.x * 256 + threadIdx.x, n = gridDim.x * 256;
  pack_fragsB(Wd, 128, wdB, 98304, tid, n);            // desc proj B-frags [24kq][8nb]
  pack_fragsB(Ws, 128, wsB, 16384, tid, n);            // std proj B-frags  [4kq][8nb]
  pack_frags(W1, 512, 1152, 4, w1f, 65536, tid, n);    // W1[1152:] A-frags [32mb][4ks]
  pack_frags(W2, 512, 0,   16, w2f, 262144, tid, n);   // W2        A-frags [32mb][16ks]
}

// ---------------- cc[b][h] = b1[h] + ctx(b).W1[:1152,h]  (fp32 exact) ----------------
__global__ __launch_bounds__(256) void ctx_cc(
    const float* __restrict__ instr, const float* __restrict__ state, const float* __restrict__ hidden,
    const float* __restrict__ W1, const float* __restrict__ b1, float* __restrict__ cc) {
  int bid = blockIdx.x;
  int b = bid >> 2, part = bid & 3;
  __shared__ float ctx[1152];
  __shared__ float red[256];
  int t = threadIdx.x;
  for (int i = t; i < 512; i += 256) { ctx[i] = instr[b * 512 + i]; ctx[512 + i] = state[b * 512 + i]; }
  if (t < 128) ctx[1024 + t] = hidden[b * 128 + t];
  __syncthreads();
  int hcol = part * 128 + (t & 127);
  int half = t >> 7;
  float acc = 0.f;
  const float* wp = W1 + (size_t)half * 576 * 512 + hcol;
  #pragma unroll 8
  for (int d = 0; d < 576; ++d) acc = fmaf(ctx[half * 576 + d], wp[(size_t)d * 512], acc);
  red[t] = acc;
  __syncthreads();
  if (t < 128) cc[b * 512 + hcol] = red[t] + red[t + 128] + b1[hcol];
}

// ---------------- q_inv[b]: MLP tail on emb=0 rows (f32 W2) ----------------
__global__ __launch_bounds__(256) void qinv_kernel(
    const float* __restrict__ cc, const float* __restrict__ W2, const float* __restrict__ b2,
    const float* __restrict__ W3, const float* __restrict__ b3, float* __restrict__ qinv) {
  int b = blockIdx.x, t = threadIdx.x;
  __shared__ float h1s[512];
  __shared__ float red[256];
  for (int i = t; i < 512; i += 256) h1s[i] = fmaxf(cc[b * 512 + i], 0.f);
  __syncthreads();
  float a0 = b2[t], a1 = b2[t + 256];
  #pragma unroll 4
  for (int c = 0; c < 512; ++c) {
    float x = h1s[c];
    a0 = fmaf(x, W2[(size_t)c * 512 + t], a0);
    a1 = fmaf(x, W2[(size_t)c * 512 + t + 256], a1);
  }
  red[t] = fmaxf(a0, 0.f) * W3[t] + fmaxf(a1, 0.f) * W3[t + 256];
  __syncthreads();
  for (int s = 128; s > 0; s >>= 1) { if (t < s) red[t] += red[t + s]; __syncthreads(); }
  if (t == 0) qinv[b] = fmaxf(red[0] + b3[0], 0.f);
}

// ---------------- E: barrier-free emb. 1 wave = one 32-row tile. grid 512 x 256thr ----------------
__global__ __launch_bounds__(256, 4) void emb_kernel(
    const float* __restrict__ adesc, const float* __restrict__ astd,
    const int* __restrict__ type_ids, const int* __restrict__ lengths,
    const float* __restrict__ bdesc, const float* __restrict__ bstd,
    const unsigned short* __restrict__ wdB, const unsigned short* __restrict__ wsB,
    float* __restrict__ embout, unsigned short* __restrict__ embB) {
  __shared__ __align__(16) unsigned short Eall[4][32 * 136];
  int t = threadIdx.x;
  int w = t >> 6, l = t & 63;
  int tile = blockIdx.x * 4 + w;
  int b = tile >> 4, lt = tile & 15;
  int l0 = lt * 32;
  int len = lengths[b];
  int nv = len - l0; nv = nv < 0 ? 0 : (nv > 32 ? 32 : nv);

  if (nv == 0) {  // wave-local zero fill; no barriers anywhere so divergent exit is safe
    f32x4 z = {0.f, 0.f, 0.f, 0.f};
    f32x4* ep = (f32x4*)(embout + (size_t)(b * 512 + l0) * 128);
    #pragma unroll
    for (int i = 0; i < 16; ++i) ep[l + i * 64] = z;
    u32x4 z4 = {0u, 0u, 0u, 0u};
    u32x4* bp = (u32x4*)(embB + (size_t)tile * 4096);
    #pragma unroll
    for (int i = 0; i < 8; ++i) bp[l + i * 64] = z4;
    return;
  }

  int ln = l & 15, g = l >> 4;
  int r0 = ln, r1 = 16 + ln;                     // A-frag rows held by this lane
  int ty0 = type_ids[b * 512 + l0 + r0];
  int ty1 = type_ids[b * 512 + l0 + r1];
  unsigned mD0 = (r0 < nv && ty0 == 0) ? 0xFFFFFFFFu : 0u;
  unsigned mD1 = (r1 < nv && ty1 == 0) ? 0xFFFFFFFFu : 0u;
  unsigned mS0 = (r0 < nv && ty0 != 0) ? 0xFFFFFFFFu : 0u;
  unsigned mS1 = (r1 < nv && ty1 != 0) ? 0xFFFFFFFFu : 0u;

  // masked lanes point at the tensor base (broadcast line) to avoid wasted fetches
  const float* dB0 = mD0 ? (adesc + (size_t)(b * 512 + l0 + r0) * 768 + g * 8) : adesc;
  const float* dB1 = mD1 ? (adesc + (size_t)(b * 512 + l0 + r1) * 768 + g * 8) : adesc;
  const float* sB0 = mS0 ? (astd  + (size_t)(b * 512 + l0 + r0) * 128 + g * 8) : astd;
  const float* sB1 = mS1 ? (astd  + (size_t)(b * 512 + l0 + r1) * 128 + g * 8) : astd;

  f32x4 acc[2][8];
  #pragma unroll
  for (int rg = 0; rg < 2; ++rg)
    #pragma unroll
    for (int nb = 0; nb < 8; ++nb) acc[rg][nb] = (f32x4){0.f, 0.f, 0.f, 0.f};

  #pragma unroll 2
  for (int kq = 0; kq < 24; ++kq) {  // desc: K = 768
    f32x4 v00 = *(const f32x4*)(dB0 + kq * 32);
    f32x4 v01 = *(const f32x4*)(dB0 + kq * 32 + 4);
    f32x4 v10 = *(const f32x4*)(dB1 + kq * 32);
    f32x4 v11 = *(const f32x4*)(dB1 + kq * 32 + 4);
    short8_t a0 = cvt8m(v00, v01, mD0);
    short8_t a1 = cvt8m(v10, v11, mD1);
    const unsigned short* bb = wdB + (size_t)kq * 4096;
    #pragma unroll
    for (int nb = 0; nb < 8; ++nb) {
      short8_t bf = *(const short8_t*)(bb + (nb * 64 + l) * 8);
      acc[0][nb] = __builtin_amdgcn_mfma_f32_16x16x32_bf16(a0, bf, acc[0][nb], 0, 0, 0);
      acc[1][nb] = __builtin_amdgcn_mfma_f32_16x16x32_bf16(a1, bf, acc[1][nb], 0, 0, 0);
    }
  }
  #pragma unroll
  for (int kq = 0; kq < 4; ++kq) {   // std: K = 128
    f32x4 v00 = *(const f32x4*)(sB0 + kq * 32);
    f32x4 v01 = *(const f32x4*)(sB0 + kq * 32 + 4);
    f32x4 v10 = *(const f32x4*)(sB1 + kq * 32);
    f32x4 v11 = *(const f32x4*)(sB1 + kq * 32 + 4);
    short8_t a0 = cvt8m(v00, v01, mS0);
    short8_t a1 = cvt8m(v10, v11, mS1);
    const unsigned short* bb = wsB + (size_t)kq * 4096;
    #pragma unroll
    for (int nb = 0; nb < 8; ++nb) {
      short8_t bf = *(const short8_t*)(bb + (nb * 64 + l) * 8);
      acc[0][nb] = __builtin_amdgcn_mfma_f32_16x16x32_bf16(a0, bf, acc[0][nb], 0, 0, 0);
      acc[1][nb] = __builtin_amdgcn_mfma_f32_16x16x32_bf16(a1, bf, acc[1][nb], 0, 0, 0);
    }
  }

  // D layout: row(M, action row within 16) = g*4+reg, col(N, emb dim) = ln
  int tyr0[4], tyr1[4];
  #pragma unroll
  for (int reg = 0; reg < 4; ++reg) {
    int ra = g * 4 + reg, rb = 16 + g * 4 + reg;
    tyr0[reg] = (ra < nv) ? type_ids[b * 512 + l0 + ra] : -1;
    tyr1[reg] = (rb < nv) ? type_ids[b * 512 + l0 + rb] : -1;
  }
  unsigned short* E = Eall[w];
  const size_t obase = (size_t)(b * 512 + l0);
  #pragma unroll
  for (int nb = 0; nb < 8; ++nb) {
    int c = nb * 16 + ln;
    float bdv = bdesc[c], bsv = bstd[c];
    #pragma unroll
    for (int reg = 0; reg < 4; ++reg) {
      {
        int r = g * 4 + reg, ty = tyr0[reg];
        float e = acc[0][nb][reg];
        e = (ty < 0) ? 0.f : e + (ty == 0 ? bdv : bsv);
        embout[(obase + r) * 128 + c] = e;
        E[r * 136 + c] = cvt1(e);
      }
      {
        int r = 16 + g * 4 + reg, ty = tyr1[reg];
        float e = acc[1][nb][reg];
        e = (ty < 0) ? 0.f : e + (ty == 0 ? bdv : bsv);
        embout[(obase + r) * 128 + c] = e;
        E[r * 136 + c] = cvt1(e);
      }
    }
  }
  // wave-private LDS transpose -> embB export (no __syncthreads: wave-local wait)
  asm volatile("s_waitcnt lgkmcnt(0)" ::: "memory");
  __builtin_amdgcn_sched_barrier(0);
  unsigned short* eb = embB + (size_t)tile * 4096;
  #pragma unroll
  for (int ks = 0; ks < 4; ++ks)
    #pragma unroll
    for (int nb2 = 0; nb2 < 2; ++nb2) {
      short8_t v = *(const short8_t*)&E[(nb2 * 16 + ln) * 136 + ks * 32 + g * 8];
      *(short8_t*)&eb[((ks * 2 + nb2) * 64 + l) * 8] = v;
    }
}

// ---------------- M: MLP. 64-row tiles, 512 threads, grid (8,128) ----------------
__global__ __launch_bounds__(512, 4) void mlp_kernel(
    const int* __restrict__ lengths,
    const float* __restrict__ b2, const float* __restrict__ W3, const float* __restrict__ b3,
    const unsigned short* __restrict__ w1f, const unsigned short* __restrict__ w2f,
    const float* __restrict__ cc, const float* __restrict__ qinv,
    const unsigned short* __restrict__ embB, float* __restrict__ qout) {
  int b = blockIdx.y, lt = blockIdx.x;
  int l0 = lt * 64;
  int t = threadIdx.x;
  int len = lengths[b];
  int nv = len - l0; nv = nv < 0 ? 0 : (nv > 64 ? 64 : nv);

  if (nv == 0) {
    if (t < 64) qout[(size_t)b * 512 + l0 + t] = qinv[b];
    return;
  }

  __shared__ __align__(16) unsigned short h1[64 * 520];
  __shared__ float qpart[8][64];
  int w = t >> 6, l = t & 63, g = l >> 4, ln = l & 15;

  // ===== S1: H1T[c1][r] = cc[b][c1] + sum_k W1e[k][c1]*emb[r][k]; b-frags prefetched 1-deep
  f32x4 acc1[4][4];
  #pragma unroll
  for (int mbi = 0; mbi < 4; ++mbi) {
    f32x4 ccv = *(const f32x4*)(cc + (size_t)b * 512 + (w * 4 + mbi) * 16 + g * 4);
    #pragma unroll
    for (int nb = 0; nb < 4; ++nb) acc1[mbi][nb] = ccv;
  }
  const unsigned short* ebase = embB + (size_t)(b * 16 + lt * 2) * 4096;
  short8_t bP[2][4];
  #pragma unroll
  for (int nb = 0; nb < 4; ++nb)
    bP[0][nb] = *(const short8_t*)&ebase[(nb >> 1) * 4096 + ((0 * 2 + (nb & 1)) * 64 + l) * 8];
  #pragma unroll
  for (int ks = 0; ks < 4; ++ks) {
    if (ks < 3) {
      #pragma unroll
      for (int nb = 0; nb < 4; ++nb)
        bP[(ks + 1) & 1][nb] =
            *(const short8_t*)&ebase[(nb >> 1) * 4096 + (((ks + 1) * 2 + (nb & 1)) * 64 + l) * 8];
    }
    #pragma unroll
    for (int mbi = 0; mbi < 4; ++mbi) {
      short8_t a = *(const short8_t*)(w1f + ((((w * 4 + mbi) * 4 + ks) * 64 + l) << 3));
      #pragma unroll
      for (int nb = 0; nb < 4; ++nb)
        acc1[mbi][nb] = __builtin_amdgcn_mfma_f32_16x16x32_bf16(a, bP[ks & 1][nb], acc1[mbi][nb], 0, 0, 0);
    }
  }
  // relu + pack H1 bf16 -> LDS
  #pragma unroll
  for (int mbi = 0; mbi < 4; ++mbi) {
    int c0 = (w * 4 + mbi) * 16 + g * 4;
    #pragma unroll
    for (int nb = 0; nb < 4; ++nb) {
      int r = nb * 16 + ln;
      f32x4 v = acc1[mbi][nb];
      short4_t p;
      p[0] = (short)cvt1(fmaxf(v[0], 0.f)); p[1] = (short)cvt1(fmaxf(v[1], 0.f));
      p[2] = (short)cvt1(fmaxf(v[2], 0.f)); p[3] = (short)cvt1(fmaxf(v[3], 0.f));
      *(short4_t*)&h1[r * 520 + c0] = p;
    }
  }
  __syncthreads();

  // ===== S2: H2T[c2][r] = b2[c2] + sum_c1 W2[c1][c2]*H1[r][c1]; a-frags prefetched 1-deep
  f32x4 acc2[4][4];
  #pragma unroll
  for (int mbi = 0; mbi < 4; ++mbi) {
    f32x4 b2v = *(const f32x4*)(b2 + (w * 4 + mbi) * 16 + g * 4);
    #pragma unroll
    for (int nb = 0; nb < 4; ++nb) acc2[mbi][nb] = b2v;
  }
  short8_t aP[2][4];
  #pragma unroll
  for (int mbi = 0; mbi < 4; ++mbi)
    aP[0][mbi] = *(const short8_t*)(w2f + ((((w * 4 + mbi) * 16 + 0) * 64 + l) << 3));
  #pragma unroll
  for (int ks = 0; ks < 16; ++ks) {
    if (ks < 15) {
      #pragma unroll
      for (int mbi = 0; mbi < 4; ++mbi)
        aP[(ks + 1) & 1][mbi] =
            *(const short8_t*)(w2f + ((((w * 4 + mbi) * 16 + (ks + 1)) * 64 + l) << 3));
    }
    short8_t bfr[4];
    #pragma unroll
    for (int nb = 0; nb < 4; ++nb)
      bfr[nb] = *(const short8_t*)&h1[(nb * 16 + ln) * 520 + ks * 32 + g * 8];
    #pragma unroll
    for (int mbi = 0; mbi < 4; ++mbi) {
      #pragma unroll
      for (int nb = 0; nb < 4; ++nb)
        acc2[mbi][nb] = __builtin_amdgcn_mfma_f32_16x16x32_bf16(aP[ks & 1][mbi], bfr[nb], acc2[mbi][nb], 0, 0, 0);
    }
  }

  // ===== S3: q[r] = relu(b3 + sum_c2 relu(H2)*W3)
  float part[4] = {0.f, 0.f, 0.f, 0.f};
  #pragma unroll
  for (int mbi = 0; mbi < 4; ++mbi) {
    int c0 = (w * 4 + mbi) * 16 + g * 4;
    f32x4 w3v = *(const f32x4*)(W3 + c0);
    #pragma unroll
    for (int nb = 0; nb < 4; ++nb) {
      f32x4 v = acc2[mbi][nb];
      part[nb] += fmaxf(v[0], 0.f) * w3v[0] + fmaxf(v[1], 0.f) * w3v[1]
                + fmaxf(v[2], 0.f) * w3v[2] + fmaxf(v[3], 0.f) * w3v[3];
    }
  }
  #pragma unroll
  for (int nb = 0; nb < 4; ++nb) {
    float p = part[nb];
    p += __shfl_xor(p, 16, 64);
    p += __shfl_xor(p, 32, 64);
    if (g == 0) qpart[w][nb * 16 + ln] = p;
  }
  __syncthreads();
  if (t < 64) {
    float q = qpart[0][t] + qpart[1][t] + qpart[2][t] + qpart[3][t]
            + qpart[4][t] + qpart[5][t] + qpart[6][t] + qpart[7][t] + b3[0];
    qout[(size_t)b * 512 + l0 + t] = fmaxf(q, 0.f);
  }
}

extern "C" void kernel_launch(void* const* d_in, const int* in_sizes, int n_in,
                              void* d_out, int out_size, void* d_ws, size_t ws_size,
                              hipStream_t stream) {
  (void)in_sizes; (void)n_in; (void)out_size; (void)ws_size;
  const float* instr  = (const float*)d_in[0];
  const float* state  = (const float*)d_in[1];
  const float* hidden = (const float*)d_in[2];
  const float* adesc  = (const float*)d_in[3];
  const float* astd   = (const float*)d_in[4];
  const int*   tids   = (const int*)d_in[5];
  const int*   lens   = (const int*)d_in[6];
  const float* Wd = (const float*)d_in[7];
  const float* bd = (const float*)d_in[8];
  const float* Ws = (const float*)d_in[9];
  const float* bs = (const float*)d_in[10];
  const float* W1 = (const float*)d_in[11];
  const float* b1 = (const float*)d_in[12];
  const float* W2 = (const float*)d_in[13];
  const float* b2 = (const float*)d_in[14];
  const float* W3 = (const float*)d_in[15];
  const float* b3 = (const float*)d_in[16];

  float* qout = (float*)d_out;
  float* embout = qout + 128 * 512;

  char* ws = (char*)d_ws;
  unsigned short* wdB  = (unsigned short*)(ws);             // 196608 B
  unsigned short* wsB  = (unsigned short*)(ws + 196608);    //  32768 B
  unsigned short* w1f  = (unsigned short*)(ws + 229376);    // 131072 B
  unsigned short* w2f  = (unsigned short*)(ws + 360448);    // 524288 B
  float* cc   = (float*)(ws + 884736);                      // 262144 B
  float* qinv = (float*)(ws + 1146880);                     // 512 B
  unsigned short* embB = (unsigned short*)(ws + 1147392);   // 16777216 B

  prep_pack<<<256, 256, 0, stream>>>(Wd, Ws, W1, W2, wdB, wsB, w1f, w2f);
  ctx_cc<<<512, 256, 0, stream>>>(instr, state, hidden, W1, b1, cc);
  qinv_kernel<<<128, 256, 0, stream>>>(cc, W2, b2, W3, b3, qinv);
  emb_kernel<<<512, 256, 0, stream>>>(adesc, astd, tids, lens, bd, bs,
                                      wdB, wsB, embout, embB);
  mlp_kernel<<<dim3(8, 128), 512, 0, stream>>>(lens, b2, W3, b3, w1f, w2f,
                                               cc, qinv, embB, qout);
}